// Round 6
// baseline (265.849 us; speedup 1.0000x reference)
//
#include <hip/hip_runtime.h>

typedef unsigned int u32;
typedef int i32x4 __attribute__((ext_vector_type(4)));
typedef int i32x16 __attribute__((ext_vector_type(16)));

#define DIN 2048              // K elements; int8 row = 2048 bytes
#define DOUT 8192
#define MROWS 8192            // B*S
#define NELEM_W (8192 * 2048)

// workspace layout (bytes)
#define WS_PART 0                        // double[2048]
#define WS_WFAC 16384                    // float
#define WS_ROWFAC 16640                  // float[8192]
#define WS_XQ 49408                      // int8[8192*2048]
#define WS_WQ (49408 + 16777216)         // int8[8192*2048]

// ---------------- weight abs-sum (stage 1) ----------------------------------
__global__ void k_wabs(const float* __restrict__ w, double* __restrict__ part) {
    const float4* w4 = (const float4*)w;
    const unsigned t = threadIdx.x, b = blockIdx.x;
    float s = 0.f;
    for (unsigned i = b * 256u + t; i < (NELEM_W / 4); i += 2048u * 256u) {
        float4 v = w4[i];
        s += fabsf(v.x) + fabsf(v.y) + fabsf(v.z) + fabsf(v.w);
    }
    double d = (double)s;
    #pragma unroll
    for (int o = 32; o; o >>= 1) d += __shfl_down(d, o);
    __shared__ double red[4];
    if ((t & 63u) == 0u) red[t >> 6] = d;
    __syncthreads();
    if (t == 0) part[b] = red[0] + red[1] + red[2] + red[3];
}

// ---------------- weight abs-mean (stage 2) ---------------------------------
__global__ void k_wfin(const double* __restrict__ part, float* __restrict__ wfac) {
    const int t = threadIdx.x;
    double s = 0.0;
    #pragma unroll
    for (int j = 0; j < 8; ++j) s += part[t + j * 256];
    #pragma unroll
    for (int o = 32; o; o >>= 1) s += __shfl_down(s, o);
    __shared__ double red[4];
    if ((t & 63) == 0) red[t >> 6] = s;
    __syncthreads();
    if (t == 0) {
        double mean = (red[0] + red[1] + red[2] + red[3]) * (1.0 / (double)NELEM_W);
        *wfac = fmaxf((float)mean, 1e-5f);
    }
}

// ---------------- fused: ternary weight quant + RMS-norm/act quant ----------
__global__ void k_prep(const float* __restrict__ w, const float* __restrict__ wfac,
                       u32* __restrict__ wq, const float* __restrict__ x,
                       u32* __restrict__ xq, float* __restrict__ rowfac) {
    const int t = threadIdx.x;
    if (blockIdx.x < 2048) {
        const float scale = 1.0f / *wfac;
        const float4* w4 = (const float4*)w;
        for (unsigned i = blockIdx.x * 256u + t; i < (NELEM_W / 4); i += 2048u * 256u) {
            float4 v = w4[i];
            int q0 = (int)fminf(fmaxf(rintf(v.x * scale), -1.f), 1.f);
            int q1 = (int)fminf(fmaxf(rintf(v.y * scale), -1.f), 1.f);
            int q2 = (int)fminf(fmaxf(rintf(v.z * scale), -1.f), 1.f);
            int q3 = (int)fminf(fmaxf(rintf(v.w * scale), -1.f), 1.f);
            wq[i] = (u32)(q0 & 255) | ((u32)(q1 & 255) << 8) |
                    ((u32)(q2 & 255) << 16) | ((u32)(q3 & 255) << 24);
        }
        return;
    }
    const int row = blockIdx.x - 2048;
    const float4* xr = (const float4*)(x + (size_t)row * DIN);
    float4 v0 = xr[t], v1 = xr[t + 256];
    float ss = v0.x * v0.x + v0.y * v0.y + v0.z * v0.z + v0.w * v0.w
             + v1.x * v1.x + v1.y * v1.y + v1.z * v1.z + v1.w * v1.w;
    __shared__ float red[4];
    #pragma unroll
    for (int o = 32; o; o >>= 1) ss += __shfl_down(ss, o);
    if ((t & 63) == 0) red[t >> 6] = ss;
    __syncthreads();
    ss = red[0] + red[1] + red[2] + red[3];
    const float r = 1.0f / sqrtf(ss * (1.0f / DIN) + 1.1920929e-7f);
    float xn[8] = {v0.x * r, v0.y * r, v0.z * r, v0.w * r,
                   v1.x * r, v1.y * r, v1.z * r, v1.w * r};
    float am = 0.f;
    #pragma unroll
    for (int j = 0; j < 8; ++j) am = fmaxf(am, fabsf(xn[j]));
    __syncthreads();
    #pragma unroll
    for (int o = 32; o; o >>= 1) am = fmaxf(am, __shfl_down(am, o));
    if ((t & 63) == 0) red[t >> 6] = am;
    __syncthreads();
    am = fmaxf(fmaxf(red[0], red[1]), fmaxf(red[2], red[3]));
    const float amc = fmaxf(am, 1e-5f);
    const float s = 127.0f / amc;
    int q[8];
    #pragma unroll
    for (int j = 0; j < 8; ++j)
        q[j] = (int)fminf(fmaxf(rintf(xn[j] * s), -128.f), 127.f);
    u32* xo = xq + (size_t)row * (DIN / 4);
    xo[t] = (u32)(q[0] & 255) | ((u32)(q[1] & 255) << 8) |
            ((u32)(q[2] & 255) << 16) | ((u32)(q[3] & 255) << 24);
    xo[t + 256] = (u32)(q[4] & 255) | ((u32)(q[5] & 255) << 8) |
                  ((u32)(q[6] & 255) << 16) | ((u32)(q[7] & 255) << 24);
    if (t == 0) rowfac[row] = amc * (1.0f / 127.0f);
}

// ---------------- 128x128 int8 GEMM, 32x32x32 MFMA, 2 blocks/CU --------------
// C[m,n] = (sum_k Xq[m,k]*Wq[n,k]) * rowfac[m] * wfac.
// 256 threads = 4 waves (2M x 2N); per-wave output 64x64 = 2x2 tiles of 32x32.
// LDS 64KB: A[slot][kh][128 rows][64B] @0, B same @32768 (slot 16KB, kh 8KB).
// 16B-granule XOR-((row>>1)&3) swizzle (r3's zero-conflict variant), inverse
// applied to per-lane GLOBAL source (rule #21). K-tile = 128B, kh = 64B = 2
// k-steps of 32. Per phase (one kh): 8 ds_read_b128; stage one kh-group (4
// gload_lds: 2A+2B) 3 phases ahead; vmcnt(8) gate; barrier; lgkmcnt(0);
// setprio(1); 8 MFMA 32x32x32; setprio(0); barrier.
// FIFO trace (steady): at phA(T) start queue=[Tkh1, T+1kh0]; phA stages
// T+1kh1, gate vmcnt(8)->Tkh1 done; phB stages T+2kh0, gate vmcnt(8)->T+1kh0.
__launch_bounds__(256, 2)
__global__ void k_gemm(const char* __restrict__ A, const char* __restrict__ Bw,
                       const float* __restrict__ rowfac, const float* __restrict__ wfac,
                       float* __restrict__ out) {
    __shared__ __attribute__((aligned(16))) char smb[65536];

    const int t = threadIdx.x;
    const int l = t & 63, w = t >> 6;
    const int wm = w >> 1, wn = w & 1;
    const int la = l & 31, lhi = l >> 5;
    // fragment read: phys granule = (ks*2 + lhi) ^ ((la>>1)&3); ks=1 flips bit1
    const int o0 = ((lhi ^ ((la >> 1) & 3)) * 16);
    const int o1 = o0 ^ 32;
    // row byte bases within a [128][64B] kh-buffer
    const int aR0 = (wm * 64 + la) * 64, aR1 = (wm * 64 + 32 + la) * 64;
    const int bR0 = (wn * 64 + la) * 64, bR1 = (wn * 64 + 32 + la) * 64;
    // stage: thread t writes LDS linear j*4096 + t*16 (row = j*64 + t/4,
    // phys granule t&3); source logical granule = (t&3) ^ ((t>>3)&3)
    const int sgl = ((t & 3) ^ ((t >> 3) & 3)) * 16;
    const int srw = t >> 2;

    // XCD-bijective block swizzle (4096 % 8 == 0)
    const int bid = blockIdx.x;
    const int wg = (bid & 7) * 512 + (bid >> 3);
    const int bm = wg >> 6, bn = wg & 63;
    const char* Ab = A + (size_t)(bm * 128) * DIN;
    const char* Bb = Bw + (size_t)(bn * 128) * DIN;

    i32x16 acc[2][2] = {};

#define STGK(tB, kh, s) do {                                                      \
    _Pragma("unroll")                                                             \
    for (int j_ = 0; j_ < 2; ++j_)                                                \
        __builtin_amdgcn_global_load_lds(                                         \
            (const __attribute__((address_space(1))) void*)(Ab + (size_t)(j_ * 64 + srw) * DIN + (tB) + (kh) * 64 + sgl), \
            (__attribute__((address_space(3))) void*)(smb + (s) * 16384 + (kh) * 8192 + j_ * 4096 + t * 16), \
            16, 0, 0);                                                            \
    _Pragma("unroll")                                                             \
    for (int j_ = 0; j_ < 2; ++j_)                                                \
        __builtin_amdgcn_global_load_lds(                                         \
            (const __attribute__((address_space(1))) void*)(Bb + (size_t)(j_ * 64 + srw) * DIN + (tB) + (kh) * 64 + sgl), \
            (__attribute__((address_space(3))) void*)(smb + 32768 + (s) * 16384 + (kh) * 8192 + j_ * 4096 + t * 16), \
            16, 0, 0);                                                            \
} while (0)

#define NOGATE ((void)0)
#define NOSTG ((void)0)
#define VM(n) asm volatile("s_waitcnt vmcnt(" #n ")" ::: "memory")

#define PHASE(s, kh, STAGE_STMT, GATE_STMT) do {                                  \
    const char* aB_ = smb + (s) * 16384 + (kh) * 8192;                            \
    const char* bB_ = aB_ + 32768;                                                \
    i32x4 fa0_[2], fa1_[2], fb0_[2], fb1_[2];                                     \
    fa0_[0] = *(const i32x4*)(aB_ + aR0 + o0);                                    \
    fa0_[1] = *(const i32x4*)(aB_ + aR1 + o0);                                    \
    fb0_[0] = *(const i32x4*)(bB_ + bR0 + o0);                                    \
    fb0_[1] = *(const i32x4*)(bB_ + bR1 + o0);                                    \
    fa1_[0] = *(const i32x4*)(aB_ + aR0 + o1);                                    \
    fa1_[1] = *(const i32x4*)(aB_ + aR1 + o1);                                    \
    fb1_[0] = *(const i32x4*)(bB_ + bR0 + o1);                                    \
    fb1_[1] = *(const i32x4*)(bB_ + bR1 + o1);                                    \
    STAGE_STMT;                                                                   \
    GATE_STMT;                                                                    \
    __builtin_amdgcn_s_barrier();                                                 \
    asm volatile("s_waitcnt lgkmcnt(0)" ::: "memory");                            \
    __builtin_amdgcn_s_setprio(1);                                                \
    _Pragma("unroll")                                                             \
    for (int mt_ = 0; mt_ < 2; ++mt_)                                             \
        _Pragma("unroll")                                                         \
        for (int nt_ = 0; nt_ < 2; ++nt_)                                         \
            acc[mt_][nt_] = __builtin_amdgcn_mfma_i32_32x32x32_i8(                \
                fa0_[mt_], fb0_[nt_], acc[mt_][nt_], 0, 0, 0);                    \
    _Pragma("unroll")                                                             \
    for (int mt_ = 0; mt_ < 2; ++mt_)                                             \
        _Pragma("unroll")                                                         \
        for (int nt_ = 0; nt_ < 2; ++nt_)                                         \
            acc[mt_][nt_] = __builtin_amdgcn_mfma_i32_32x32x32_i8(                \
                fa1_[mt_], fb1_[nt_], acc[mt_][nt_], 0, 0, 0);                    \
    __builtin_amdgcn_s_setprio(0);                                                \
    __builtin_amdgcn_s_barrier();                                                 \
} while (0)

    // prologue: T0 kh0+kh1 -> slot0, T1 kh0 -> slot1 (12 loads); gate T0
    STGK(0, 0, 0);
    STGK(0, 1, 0);
    STGK(128, 0, 1);
    VM(4);
    __builtin_amdgcn_s_barrier();

    #pragma unroll 1
    for (int it = 0; it < 14; ++it) {               // tiles 0..13
        const int s = it & 1;
        const int tB = it * 128;
        if (s == 0) {
            PHASE(0, 0, STGK(tB + 128, 1, 1), VM(8));   // stage T+1 kh1
            PHASE(0, 1, STGK(tB + 256, 0, 0), VM(8));   // stage T+2 kh0
        } else {
            PHASE(1, 0, STGK(tB + 128, 1, 0), VM(8));
            PHASE(1, 1, STGK(tB + 256, 0, 1), VM(8));
        }
    }
    // tile 14 (slot 0): stage T15 kh1; then drain
    PHASE(0, 0, STGK(1920, 1, 1), VM(8));
    PHASE(0, 1, NOSTG, VM(4));
    // tile 15 (slot 1)
    PHASE(1, 0, NOSTG, VM(0));
    PHASE(1, 1, NOSTG, NOGATE);

    // epilogue: exact int32 -> fp32, dequant, store.
    // 32x32 C/D: col = l&31, row = (reg&3) + 8*(reg>>2) + 4*(l>>5)
    const float wf = *wfac;
    const int gcol0 = bn * 128 + wn * 64 + la;
    #pragma unroll
    for (int mt = 0; mt < 2; ++mt) {
        #pragma unroll
        for (int reg = 0; reg < 16; ++reg) {
            const int grow = bm * 128 + wm * 64 + mt * 32 +
                             (reg & 3) + 8 * (reg >> 2) + 4 * lhi;
            const float s = rowfac[grow] * wf;
            const size_t ob = (size_t)grow * DOUT + gcol0;
            out[ob]      = (float)acc[mt][0][reg] * s;
            out[ob + 32] = (float)acc[mt][1][reg] * s;
        }
    }
#undef STGK
#undef PHASE
#undef NOGATE
#undef NOSTG
#undef VM
}

extern "C" void kernel_launch(void* const* d_in, const int* in_sizes, int n_in,
                              void* d_out, int out_size, void* d_ws, size_t ws_size,
                              hipStream_t stream) {
    const float* x = (const float*)d_in[0];   // [4,2048,2048]
    const float* wt = (const float*)d_in[1];  // [8192,2048]
    float* out = (float*)d_out;               // [4,2048,8192] fp32
    char* ws = (char*)d_ws;

    double* part = (double*)(ws + WS_PART);
    float* wfac = (float*)(ws + WS_WFAC);
    float* rowfac = (float*)(ws + WS_ROWFAC);
    u32* xq = (u32*)(ws + WS_XQ);
    u32* wq = (u32*)(ws + WS_WQ);

    k_wabs<<<2048, 256, 0, stream>>>(wt, part);
    k_wfin<<<1, 256, 0, stream>>>(part, wfac);
    k_prep<<<2048 + MROWS, 256, 0, stream>>>(wt, wfac, wq, x, xq, rowfac);
    k_gemm<<<4096, 256, 0, stream>>>((const char*)xq, (const char*)wq, rowfac, wfac, out);
}

// Round 7
// 210.065 us; speedup vs baseline: 1.2656x; 1.2656x over previous
//
#include <hip/hip_runtime.h>

typedef unsigned int u32;
typedef int i32x4 __attribute__((ext_vector_type(4)));
typedef int i32x16 __attribute__((ext_vector_type(16)));

#define DIN 2048              // K elements; int8 row = 2048 bytes
#define DOUT 8192
#define MROWS 8192            // B*S
#define NELEM_W (8192 * 2048)

// workspace layout (bytes)
#define WS_PART 0                        // double[2048]
#define WS_WFAC 16384                    // float
#define WS_ROWFAC 16640                  // float[8192]
#define WS_XQ 49408                      // int8[8192*2048]
#define WS_WQ (49408 + 16777216)         // int8[8192*2048]

// ---------------- weight abs-sum (stage 1) ----------------------------------
__global__ void k_wabs(const float* __restrict__ w, double* __restrict__ part) {
    const float4* w4 = (const float4*)w;
    const unsigned t = threadIdx.x, b = blockIdx.x;
    float s = 0.f;
    for (unsigned i = b * 256u + t; i < (NELEM_W / 4); i += 2048u * 256u) {
        float4 v = w4[i];
        s += fabsf(v.x) + fabsf(v.y) + fabsf(v.z) + fabsf(v.w);
    }
    double d = (double)s;
    #pragma unroll
    for (int o = 32; o; o >>= 1) d += __shfl_down(d, o);
    __shared__ double red[4];
    if ((t & 63u) == 0u) red[t >> 6] = d;
    __syncthreads();
    if (t == 0) part[b] = red[0] + red[1] + red[2] + red[3];
}

// ---------------- weight abs-mean (stage 2) ---------------------------------
__global__ void k_wfin(const double* __restrict__ part, float* __restrict__ wfac) {
    const int t = threadIdx.x;
    double s = 0.0;
    #pragma unroll
    for (int j = 0; j < 8; ++j) s += part[t + j * 256];
    #pragma unroll
    for (int o = 32; o; o >>= 1) s += __shfl_down(s, o);
    __shared__ double red[4];
    if ((t & 63) == 0) red[t >> 6] = s;
    __syncthreads();
    if (t == 0) {
        double mean = (red[0] + red[1] + red[2] + red[3]) * (1.0 / (double)NELEM_W);
        *wfac = fmaxf((float)mean, 1e-5f);
    }
}

// ---------------- fused: ternary weight quant + RMS-norm/act quant ----------
__global__ void k_prep(const float* __restrict__ w, const float* __restrict__ wfac,
                       u32* __restrict__ wq, const float* __restrict__ x,
                       u32* __restrict__ xq, float* __restrict__ rowfac) {
    const int t = threadIdx.x;
    if (blockIdx.x < 2048) {
        const float scale = 1.0f / *wfac;
        const float4* w4 = (const float4*)w;
        for (unsigned i = blockIdx.x * 256u + t; i < (NELEM_W / 4); i += 2048u * 256u) {
            float4 v = w4[i];
            int q0 = (int)fminf(fmaxf(rintf(v.x * scale), -1.f), 1.f);
            int q1 = (int)fminf(fmaxf(rintf(v.y * scale), -1.f), 1.f);
            int q2 = (int)fminf(fmaxf(rintf(v.z * scale), -1.f), 1.f);
            int q3 = (int)fminf(fmaxf(rintf(v.w * scale), -1.f), 1.f);
            wq[i] = (u32)(q0 & 255) | ((u32)(q1 & 255) << 8) |
                    ((u32)(q2 & 255) << 16) | ((u32)(q3 & 255) << 24);
        }
        return;
    }
    const int row = blockIdx.x - 2048;
    const float4* xr = (const float4*)(x + (size_t)row * DIN);
    float4 v0 = xr[t], v1 = xr[t + 256];
    float ss = v0.x * v0.x + v0.y * v0.y + v0.z * v0.z + v0.w * v0.w
             + v1.x * v1.x + v1.y * v1.y + v1.z * v1.z + v1.w * v1.w;
    __shared__ float red[4];
    #pragma unroll
    for (int o = 32; o; o >>= 1) ss += __shfl_down(ss, o);
    if ((t & 63) == 0) red[t >> 6] = ss;
    __syncthreads();
    ss = red[0] + red[1] + red[2] + red[3];
    const float r = 1.0f / sqrtf(ss * (1.0f / DIN) + 1.1920929e-7f);
    float xn[8] = {v0.x * r, v0.y * r, v0.z * r, v0.w * r,
                   v1.x * r, v1.y * r, v1.z * r, v1.w * r};
    float am = 0.f;
    #pragma unroll
    for (int j = 0; j < 8; ++j) am = fmaxf(am, fabsf(xn[j]));
    __syncthreads();
    #pragma unroll
    for (int o = 32; o; o >>= 1) am = fmaxf(am, __shfl_down(am, o));
    if ((t & 63) == 0) red[t >> 6] = am;
    __syncthreads();
    am = fmaxf(fmaxf(red[0], red[1]), fmaxf(red[2], red[3]));
    const float amc = fmaxf(am, 1e-5f);
    const float s = 127.0f / amc;
    int q[8];
    #pragma unroll
    for (int j = 0; j < 8; ++j)
        q[j] = (int)fminf(fmaxf(rintf(xn[j] * s), -128.f), 127.f);
    u32* xo = xq + (size_t)row * (DIN / 4);
    xo[t] = (u32)(q[0] & 255) | ((u32)(q[1] & 255) << 8) |
            ((u32)(q[2] & 255) << 16) | ((u32)(q[3] & 255) << 24);
    xo[t + 256] = (u32)(q[4] & 255) | ((u32)(q[5] & 255) << 8) |
                  ((u32)(q[6] & 255) << 16) | ((u32)(q[7] & 255) << 24);
    if (t == 0) rowfac[row] = amc * (1.0f / 127.0f);
}

// ---------------- 256x256 int8 GEMM, within-wave SW pipeline -----------------
// C[m,n] = (sum_k Xq[m,k]*Wq[n,k]) * rowfac[m] * wfac.
// 8 waves (2M x 4N), wave tile 128x64, MFMA i32_32x32x32_i8 (4m x 2n, acc 128).
// LDS 128KB: A slot0@0, A slot1@32768, B slot0@65536, B slot1@98304;
// each slot [256 rows][128B K-tile]. 16B-granule XOR-(row&7) swizzle, inverse
// applied to per-lane GLOBAL source (rule #21); reads land 8 lanes/4-bank
// group = conflict-free b128 floor.
// Per ks-step (32 elem): issue 6 ds_read_b128 for ks+1, run 8 MFMA on ks
// (reads drain under MFMA via compiler's counted lgkmcnt). Per K-tile:
// lgkmcnt(0)+barrier -> STG(T+2 -> same slot) -> vmcnt(8) counted -> barrier
// -> RD(T+1,ks0) -> tail MFMA. Staging stays 2 tiles deep, never vmcnt(0).
__launch_bounds__(512, 2)
__global__ void k_gemm(const char* __restrict__ A, const char* __restrict__ Bw,
                       const float* __restrict__ rowfac, const float* __restrict__ wfac,
                       float* __restrict__ out) {
    __shared__ __attribute__((aligned(16))) char smb[131072];

    const int t = threadIdx.x;
    const int l = t & 63, w = t >> 6;
    const int wm = w >> 2, wn = w & 3;
    const int la = l & 31, lhi = l >> 5;
    const int swz = la & 7;
    // granule byte-offsets for ks = 0..3 (phys granule = (ks*2+lhi) ^ swz)
    const int o0 = ((lhi ^ swz) * 16);
    const int o1 = (((2 + lhi) ^ swz) * 16);
    const int o2 = (((4 + lhi) ^ swz) * 16);
    const int o3 = (((6 + lhi) ^ swz) * 16);
    // row byte bases (m/n tile strides are compile-time 4096)
    const int aRow = (wm * 128 + la) * 128;
    const int bRow = (wn * 64 + la) * 128;
    // stage: thread t writes LDS linear j*8192 + t*16 (row = j*64 + t/8,
    // phys granule t&7); source logical granule = (t&7) ^ ((t>>3)&7)
    const int srw = t >> 3;
    const int sgl = ((t & 7) ^ (srw & 7)) * 16;

    // XCD-bijective block swizzle (1024 % 8 == 0)
    const int bid = blockIdx.x;
    const int wg = (bid & 7) * 128 + (bid >> 3);
    const int bm = wg >> 5, bn = wg & 31;
    const char* Ab = A + (size_t)(bm * 256) * DIN;
    const char* Bb = Bw + (size_t)(bn * 256) * DIN;

    i32x16 acc[4][2] = {};
    i32x4 a0[4], b0[2], a1[4], b1[2];

#define STG(tB, SOFF) do {                                                        \
    _Pragma("unroll")                                                             \
    for (int j_ = 0; j_ < 4; ++j_) {                                              \
        __builtin_amdgcn_global_load_lds(                                         \
            (const __attribute__((address_space(1))) void*)(Ab + (size_t)(j_ * 64 + srw) * DIN + (tB) + sgl), \
            (__attribute__((address_space(3))) void*)(smb + (SOFF) + j_ * 8192 + t * 16), 16, 0, 0); \
        __builtin_amdgcn_global_load_lds(                                         \
            (const __attribute__((address_space(1))) void*)(Bb + (size_t)(j_ * 64 + srw) * DIN + (tB) + sgl), \
            (__attribute__((address_space(3))) void*)(smb + 65536 + (SOFF) + j_ * 8192 + t * 16), 16, 0, 0); \
    }                                                                             \
} while (0)

#define RD(SOFF, KO, fa, fb) do {                                                 \
    const char* aS_ = smb + (SOFF);                                               \
    const char* bS_ = smb + 65536 + (SOFF);                                       \
    _Pragma("unroll")                                                             \
    for (int m_ = 0; m_ < 4; ++m_)                                                \
        fa[m_] = *(const i32x4*)(aS_ + aRow + m_ * 4096 + (KO));                  \
    _Pragma("unroll")                                                             \
    for (int n_ = 0; n_ < 2; ++n_)                                                \
        fb[n_] = *(const i32x4*)(bS_ + bRow + n_ * 4096 + (KO));                  \
} while (0)

#define MFMA8(fa, fb) do {                                                        \
    __builtin_amdgcn_s_setprio(1);                                                \
    _Pragma("unroll")                                                             \
    for (int m_ = 0; m_ < 4; ++m_)                                                \
        _Pragma("unroll")                                                         \
        for (int n_ = 0; n_ < 2; ++n_)                                            \
            acc[m_][n_] = __builtin_amdgcn_mfma_i32_32x32x32_i8(                  \
                fa[m_], fb[n_], acc[m_][n_], 0, 0, 0);                            \
    __builtin_amdgcn_s_setprio(0);                                                \
} while (0)

#define LGKM0 asm volatile("s_waitcnt lgkmcnt(0)" ::: "memory")
#define VM(n) asm volatile("s_waitcnt vmcnt(" #n ")" ::: "memory")
#define BAR __builtin_amdgcn_s_barrier()

// one K-tile: compute tile T from slot SOFF; stage T+2 into same slot;
// gate T+1 (counted) and preload its ks0 from the other slot.
#define TILE_FULL(SOFF, OSOFF, stgB, GATEN) do {                                  \
    RD(SOFF, o1, a1, b1);                                                         \
    MFMA8(a0, b0);                                                                \
    RD(SOFF, o2, a0, b0);                                                         \
    MFMA8(a1, b1);                                                                \
    RD(SOFF, o3, a1, b1);                                                         \
    MFMA8(a0, b0);                                                                \
    LGKM0;                                                                        \
    BAR;                      /* all waves done reading slot SOFF */              \
    STG(stgB, SOFF);          /* T+2 -> just-freed slot */                        \
    VM(GATEN);                /* oldest 8 (T+1's) complete */                     \
    BAR;                      /* T+1 resident for all waves */                    \
    RD(OSOFF, o0, a0, b0);    /* preload T+1 ks0 */                               \
    MFMA8(a1, b1);            /* tail: T ks3, hides the RD drain */               \
} while (0)

    // prologue: stage T0->slot0, T1->slot1; gate T0; preload ks0
    STG(0, 0);
    STG(128, 32768);
    VM(8);
    BAR;
    RD(0, o0, a0, b0);

    #pragma unroll 1
    for (int it = 0; it < 7; ++it) {      // tiles T=2it (slot0), T=2it+1 (slot1)
        const int tB = it * 256;
        TILE_FULL(0,     32768, tB + 256, 8);
        TILE_FULL(32768, 0,     tB + 384, 8);
    }
    // T=14 (slot0): no more staging; drain all (only T15's 8 outstanding)
    RD(0, o1, a1, b1);
    MFMA8(a0, b0);
    RD(0, o2, a0, b0);
    MFMA8(a1, b1);
    RD(0, o3, a1, b1);
    MFMA8(a0, b0);
    LGKM0;
    VM(0);
    BAR;
    RD(32768, o0, a0, b0);
    MFMA8(a1, b1);
    // T=15 (slot1): straight-line finish
    RD(32768, o1, a1, b1);
    MFMA8(a0, b0);
    RD(32768, o2, a0, b0);
    MFMA8(a1, b1);
    RD(32768, o3, a1, b1);
    MFMA8(a0, b0);
    MFMA8(a1, b1);

    // epilogue: exact int32 -> fp32, dequant, store.
    // 32x32 C/D: col = la, rowInTile = (reg&3) + 8*(reg>>2) + 4*lhi
    const float wf = *wfac;
    const int gcol0 = bn * 256 + wn * 64 + la;
    #pragma unroll
    for (int mt = 0; mt < 4; ++mt) {
        #pragma unroll
        for (int reg = 0; reg < 16; ++reg) {
            const int grow = bm * 256 + wm * 128 + mt * 32 +
                             (reg & 3) + 8 * (reg >> 2) + 4 * lhi;
            const float s = rowfac[grow] * wf;
            const size_t ob = (size_t)grow * DOUT + gcol0;
            out[ob]      = (float)acc[mt][0][reg] * s;
            out[ob + 32] = (float)acc[mt][1][reg] * s;
        }
    }
#undef STG
#undef RD
#undef MFMA8
#undef LGKM0
#undef VM
#undef BAR
#undef TILE_FULL
}

extern "C" void kernel_launch(void* const* d_in, const int* in_sizes, int n_in,
                              void* d_out, int out_size, void* d_ws, size_t ws_size,
                              hipStream_t stream) {
    const float* x = (const float*)d_in[0];   // [4,2048,2048]
    const float* wt = (const float*)d_in[1];  // [8192,2048]
    float* out = (float*)d_out;               // [4,2048,8192] fp32
    char* ws = (char*)d_ws;

    double* part = (double*)(ws + WS_PART);
    float* wfac = (float*)(ws + WS_WFAC);
    float* rowfac = (float*)(ws + WS_ROWFAC);
    u32* xq = (u32*)(ws + WS_XQ);
    u32* wq = (u32*)(ws + WS_WQ);

    k_wabs<<<2048, 256, 0, stream>>>(wt, part);
    k_wfin<<<1, 256, 0, stream>>>(part, wfac);
    k_prep<<<2048 + MROWS, 256, 0, stream>>>(wt, wfac, wq, x, xq, rowfac);
    k_gemm<<<1024, 512, 0, stream>>>((const char*)xq, (const char*)wq, rowfac, wfac, out);
}